// Round 17
// baseline (502.180 us; speedup 1.0000x reference)
//
#include <hip/hip_runtime.h>
#include <hip/hip_fp16.h>
#include <math.h>

#define NUM_BASIS 8
#define SQRT3 1.7320508075688772f
#define SQRT2 1.4142135623730951f
#define INV_SQRT_DEG 0.17677669529663687f   // 1/sqrt(32)
#define PI_F 3.14159265358979323846f

typedef _Float16 half8 __attribute__((ext_vector_type(8)));
typedef float float4v __attribute__((ext_vector_type(4)));

__device__ __forceinline__ float sigmoidf_(float x) { return 1.0f / (1.0f + __expf(-x)); }
__device__ __forceinline__ float siluf_(float x) { return x * sigmoidf_(x); }

__device__ __forceinline__ void unp2(unsigned u, float& a, float& b) {
    __half2 h = *reinterpret_cast<__half2*>(&u);
    float2 f = __half22float2(h);
    a = f.x; b = f.y;
}
__device__ __forceinline__ unsigned pk2(float a, float b) {
    __half2 h = __floats2half2_rn(a, b);
    return *reinterpret_cast<unsigned*>(&h);
}

// ---------------------------------------------------------------------------
// CSR build: degree count (4 edges/thread) -> single-block scan -> scatter
// ---------------------------------------------------------------------------
__global__ __launch_bounds__(256) void count_deg(
    const int* __restrict__ dst, int* __restrict__ deg, int E)
{
    int base = (blockIdx.x * blockDim.x + threadIdx.x) * 4;
    if (base + 3 < E) {
        int4 d4 = *(const int4*)(dst + base);
        atomicAdd(&deg[d4.x], 1);
        atomicAdd(&deg[d4.y], 1);
        atomicAdd(&deg[d4.z], 1);
        atomicAdd(&deg[d4.w], 1);
    } else {
        for (int e = base; e < E; e++) atomicAdd(&deg[dst[e]], 1);
    }
}

__global__ __launch_bounds__(1024) void scan_deg(
    const int* __restrict__ deg, int* __restrict__ cursor, int N)
{
    __shared__ int wsum[16];
    __shared__ int carry_s, tot_s;
    int tid = threadIdx.x;
    int wid = tid >> 6, lane = tid & 63;
    if (tid == 0) carry_s = 0;
    __syncthreads();
    for (int base = 0; base < N; base += 16384) {
        int i0 = base + tid * 16;
        int v[16];
        int sum = 0;
        #pragma unroll
        for (int k = 0; k < 16; k++) {
            int i = i0 + k;
            v[k] = (i < N) ? deg[i] : 0;
            sum += v[k];
        }
        int incl = sum;
        #pragma unroll
        for (int off = 1; off < 64; off <<= 1) {
            int t = __shfl_up(incl, off);
            if (lane >= off) incl += t;
        }
        if (lane == 63) wsum[wid] = incl;
        __syncthreads();
        if (wid == 0 && lane < 16) {
            int wv = wsum[lane];
            int wincl = wv;
            #pragma unroll
            for (int off = 1; off < 16; off <<= 1) {
                int t = __shfl_up(wincl, off);
                if (lane >= off) wincl += t;
            }
            wsum[lane] = wincl - wv;
            if (lane == 15) tot_s = wincl;
        }
        __syncthreads();
        int carry = carry_s;
        int run = carry + wsum[wid] + incl - sum;   // exclusive prefix at i0
        #pragma unroll
        for (int k = 0; k < 16; k++) {
            int i = i0 + k;
            if (i < N) cursor[i] = run;
            run += v[k];
        }
        __syncthreads();
        if (tid == 0) carry_s = carry + tot_s;
        __syncthreads();
    }
}

// Per-edge geometry + radial embedding, scattered directly into CSR slots.
// emb stored f16x8 (16B), y14 stored f16x4 (8B).
__global__ __launch_bounds__(256) void edge_pre_scatter(
    const float* __restrict__ pos, const int* __restrict__ src,
    const int* __restrict__ dst, const float* __restrict__ cs,
    const float* __restrict__ cell, const int* __restrict__ img,
    int* __restrict__ cursor, _Float16* __restrict__ emb,
    uint2* __restrict__ y14, int2* __restrict__ sdp, int E)
{
    int e = blockIdx.x * blockDim.x + threadIdx.x;
    if (e >= E) return;
    int si = src[e], di = dst[e];
    int slot = atomicAdd(&cursor[di], 1);
    sdp[slot] = make_int2(si, di);
    float vx = pos[di*3+0] - pos[si*3+0];
    float vy = pos[di*3+1] - pos[si*3+1];
    float vz = pos[di*3+2] - pos[si*3+2];
    float c0 = cs[(size_t)e*3+0], c1 = cs[(size_t)e*3+1], c2 = cs[(size_t)e*3+2];
    const float* M = cell + (size_t)img[si] * 9;
    vx += c0*M[0] + c1*M[3] + c2*M[6];
    vy += c0*M[1] + c1*M[4] + c2*M[7];
    vz += c0*M[2] + c1*M[5] + c2*M[8];
    float r  = sqrtf(vx*vx + vy*vy + vz*vz);
    float rs = fmaxf(r, 1e-9f);
    float inv = 1.0f / rs;
    uint2 yv;
    yv.x = pk2(SQRT3*vx*inv, SQRT3*vy*inv);
    yv.y = pk2(SQRT3*vz*inv, 0.f);
    y14[slot] = yv;
    // polynomial cutoff p=6: 1 - 28 x^6 + 48 x^7 - 21 x^8 (0 for x>=1)
    float x = r * (1.0f / 5.0f);
    float x2 = x*x, x6 = x2*x2*x2;
    float fc = 1.0f - 28.0f*x6 + 48.0f*x6*x - 21.0f*x6*x2;
    if (x >= 1.0f) fc = 0.0f;
    float pre = sqrtf(2.0f / 5.0f) * inv * fc;
    float t = PI_F * rs * (1.0f / 5.0f);
    half8 ev;
    #pragma unroll
    for (int n = 1; n <= NUM_BASIS; n++)
        ev[n-1] = (_Float16)(pre * __sinf((float)n * t));
    *(half8*)(emb + (size_t)slot*NUM_BASIS) = ev;
}

// ---------------------------------------------------------------------------
// Weight prep: w2f (W2 -> f16 B-frag), wgtf (Wg/Ws/Wv -> f16 B-frag),
// wl12 = Wl1 @ Wl2.
// ---------------------------------------------------------------------------
__global__ __launch_bounds__(256) void prep_weights(
    const float* __restrict__ W2, _Float16* __restrict__ w2f,
    const float* __restrict__ Wg, const float* __restrict__ Ws,
    const float* __restrict__ Wv, _Float16* __restrict__ wgtf,
    const float* __restrict__ Wl1, const float* __restrict__ Wl2,
    float* __restrict__ wl12)
{
    int idx = blockIdx.x * blockDim.x + threadIdx.x;
    if (idx < 64) {
        float a = 0.f;
        #pragma unroll
        for (int j = 0; j < 16; j++) a = fmaf(Wl1[idx*16 + j], Wl2[j], a);
        wl12[idx] = a;
    }
    if (idx < 3 * 20480) {
        int L  = idx / 20480;
        int r  = idx % 20480;
        int cg = r / 5120;
        int r2 = r % 5120;
        int p  = r2 / 1024;
        int r3 = r2 % 1024;
        int kh = r3 / 512;
        int r4 = r3 % 512;
        int lane = r4 / 8;
        int j  = r4 % 8;
        int k = kh*32 + (lane >> 4)*8 + j;
        int n = p*64 + cg*16 + (lane & 15);
        w2f[idx] = (_Float16)W2[(size_t)L*20480 + k*320 + n];
    } else if (idx < 3*20480 + 3*3*4096) {
        int idx2 = idx - 3*20480;
        int L   = idx2 / 12288;
        int rem = idx2 % 12288;
        int mat = rem / 4096;
        int r2  = rem % 4096;
        int cg  = r2 / 1024;
        int r3  = r2 % 1024;
        int kh  = r3 / 512;
        int r4  = r3 % 512;
        int lane = r4 / 8;
        int j   = r4 % 8;
        int k = kh*32 + (lane >> 4)*8 + j;
        int n = cg*16 + (lane & 15);
        const float* src = (mat == 0) ? Wg : (mat == 1) ? Ws : Wv;
        wgtf[idx2] = (_Float16)src[(size_t)L*4096 + k*64 + n];
    }
}

// ---------------------------------------------------------------------------
// A-frag MLP1: h[k] for edge eA (f16 emb input), k = kh*32 + q*8 + j
// ---------------------------------------------------------------------------
__device__ __forceinline__ void mlp1_afrag(
    const _Float16* __restrict__ emb, const float* __restrict__ W1,
    const float* __restrict__ B1, int eA, int q, half8 afrag[2])
{
    half8 ev = *(const half8*)(emb + (size_t)eA*8);
    float em[8];
    #pragma unroll
    for (int j = 0; j < 8; j++) em[j] = (float)ev[j];
    #pragma unroll
    for (int kh = 0; kh < 2; kh++) {
        int kb = kh*32 + q*8;
        float hv[8];
        float4 b0 = *(const float4*)(B1 + kb);
        float4 b1 = *(const float4*)(B1 + kb + 4);
        hv[0]=b0.x; hv[1]=b0.y; hv[2]=b0.z; hv[3]=b0.w;
        hv[4]=b1.x; hv[5]=b1.y; hv[6]=b1.z; hv[7]=b1.w;
        #pragma unroll
        for (int jj = 0; jj < 8; jj++) {
            float4 wa = *(const float4*)(W1 + jj*64 + kb);
            float4 wb = *(const float4*)(W1 + jj*64 + kb + 4);
            hv[0] = fmaf(em[jj], wa.x, hv[0]);
            hv[1] = fmaf(em[jj], wa.y, hv[1]);
            hv[2] = fmaf(em[jj], wa.z, hv[2]);
            hv[3] = fmaf(em[jj], wa.w, hv[3]);
            hv[4] = fmaf(em[jj], wb.x, hv[4]);
            hv[5] = fmaf(em[jj], wb.y, hv[5]);
            hv[6] = fmaf(em[jj], wb.z, hv[6]);
            hv[7] = fmaf(em[jj], wb.w, hv[7]);
        }
        #pragma unroll
        for (int j = 0; j < 8; j++)
            afrag[kh][j] = (_Float16)siluf_(hv[j]);
    }
}

// R17: staging barrier moved AFTER MLP1 (metadata/prefetch/MLP1 touch no LDS,
// so the 40KB global->LDS staging drains under ~1000 cyc of VALU instead of
// stalling at an immediate syncthreads). Early-return replaced by an `active`
// guard with clamped indices — every wave must reach the barrier.
// Cross-quad carry kept (R14: removal -> same-address atomic serialization).
// agg PLANAR (R9). No VGPR caps (R4).
// ---------------------------------------------------------------------------
// Layer-0 edge kernel: v == 0 exactly -> only w1/w3 paths, 16 MFMA, no nf.
// ---------------------------------------------------------------------------
__global__ __launch_bounds__(256) void edge_msg_mfma_l0(
    const _Float16* __restrict__ emb, const uint2* __restrict__ y14,
    const int2* __restrict__ sdp,
    const int* __restrict__ type, const float* __restrict__ wlin,
    const float* __restrict__ W1, const float* __restrict__ B1,
    const _Float16* __restrict__ w2f,
    float* __restrict__ aggs, float* __restrict__ aggx,
    float* __restrict__ aggy, float* __restrict__ aggz, int E)
{
    __shared__ _Float16 w2s[20480];   // 40 KB
    {
        half8* dstv = (half8*)w2s;
        const half8* srcv = (const half8*)w2f;
        #pragma unroll
        for (int k = 0; k < 10; k++)
            dstv[threadIdx.x + k*256] = srcv[threadIdx.x + k*256];
    }
    // NO barrier yet — MLP1 below covers the staging latency.

    int wave  = (blockIdx.x * blockDim.x + threadIdx.x) >> 6;
    int lane  = threadIdx.x & 63;
    int wbase = wave * 16;
    bool active = wbase < E;
    int q   = lane >> 4;
    int col = lane & 15;

    int eb = wbase + q*4;
    int d[4], tt[4];
    float y1x[4], y1y[4], y1z[4];
    #pragma unroll
    for (int r = 0; r < 4; r++) {
        int ee = eb + r;
        int ec = (active && ee < E) ? ee : 0;
        int2 sv = sdp[ec];
        tt[r] = type[sv.x];
        d[r]  = (active && ee < E) ? sv.y : -1;
        uint2 yv = y14[ec];
        float dummy;
        unp2(yv.x, y1x[r], y1y[r]);
        unp2(yv.y, y1z[r], dummy);
    }

    half8 afrag[2];
    mlp1_afrag(emb, W1, B1, active ? (wbase + col) : 0, q, afrag);

    int dnq = __shfl_down(d[0], 16);      // next quad's first dst
    int nd3 = (q == 3) ? -1 : dnq;        // q3 reg3: forced tail
    int df = d[0], dl = d[3];
    bool U = (df == dl);
    int dlp = __shfl_up(dl, 16);
    bool link = (q > 0) && (dlp == df);

    __syncthreads();   // staging complete; all waves arrive

    #pragma unroll
    for (int cg = 0; cg < 4; cg++) {
        float4v a1 = {0,0,0,0}, a3 = {0,0,0,0};
        const _Float16* wbp = w2s + ((size_t)cg*5*2*64*8) + (size_t)lane*8;
        {
            half8 b10 = *(const half8*)(wbp + ((size_t)(0*2 + 0))*64*8);
            half8 b11 = *(const half8*)(wbp + ((size_t)(0*2 + 1))*64*8);
            half8 b30 = *(const half8*)(wbp + ((size_t)(2*2 + 0))*64*8);
            half8 b31 = *(const half8*)(wbp + ((size_t)(2*2 + 1))*64*8);
            a1 = __builtin_amdgcn_mfma_f32_16x16x32_f16(afrag[0], b10, a1, 0, 0, 0);
            a1 = __builtin_amdgcn_mfma_f32_16x16x32_f16(afrag[1], b11, a1, 0, 0, 0);
            a3 = __builtin_amdgcn_mfma_f32_16x16x32_f16(afrag[0], b30, a3, 0, 0, 0);
            a3 = __builtin_amdgcn_mfma_f32_16x16x32_f16(afrag[1], b31, a3, 0, 0, 0);
        }
        if (!active) continue;
        int c = cg*16 + col;

        float ms[4], mx[4], my[4], mz[4];
        #pragma unroll
        for (int r = 0; r < 4; r++) {
            float s = wlin[tt[r]*64 + c];
            float w3s = a3[r] * s;
            ms[r] = a1[r] * s;
            mx[r] = w3s * y1x[r];
            my[r] = w3s * y1y[r];
            mz[r] = w3s * y1z[r];
        }
        #pragma unroll
        for (int r = 1; r < 4; r++) {
            if (d[r] == d[r-1]) {
                ms[r] += ms[r-1]; mx[r] += mx[r-1];
                my[r] += my[r-1]; mz[r] += mz[r-1];
            }
        }
        // cross-quad carry (chains up to 4 quads -> 3 iterations)
        float Cs = 0.f, Cx = 0.f, Cy = 0.f, Cz = 0.f;
        #pragma unroll
        for (int it = 0; it < 3; it++) {
            float es = ms[3] + (U ? Cs : 0.f);
            float ex = mx[3] + (U ? Cx : 0.f);
            float ey = my[3] + (U ? Cy : 0.f);
            float ez = mz[3] + (U ? Cz : 0.f);
            float ts = __shfl_up(es, 16);
            float tx = __shfl_up(ex, 16);
            float ty = __shfl_up(ey, 16);
            float tz = __shfl_up(ez, 16);
            Cs = link ? ts : 0.f; Cx = link ? tx : 0.f;
            Cy = link ? ty : 0.f; Cz = link ? tz : 0.f;
        }
        bool hr = true;
        #pragma unroll
        for (int r = 0; r < 4; r++) {
            if (r > 0) hr = hr && (d[r] == d[r-1]);
            float fs = ms[r] + (hr ? Cs : 0.f);
            float fx = mx[r] + (hr ? Cx : 0.f);
            float fy = my[r] + (hr ? Cy : 0.f);
            float fz = mz[r] + (hr ? Cz : 0.f);
            int ndx = (r < 3) ? d[r+1] : nd3;
            if (ndx != d[r] && d[r] >= 0) {
                size_t ai = (size_t)d[r]*64 + c;
                atomicAdd(aggs + ai, fs);
                atomicAdd(aggx + ai, fx);
                atomicAdd(aggy + ai, fy);
                atomicAdd(aggz + ai, fz);
            }
        }
    }
}

// ---------------------------------------------------------------------------
// General MFMA edge kernel (layers >= 1): one wave per 16 CSR edges.
// R11 batched nf prefetch (ILP over MLP1). R17 late barrier.
// ---------------------------------------------------------------------------
__global__ __launch_bounds__(256) void edge_msg_mfma(
    const _Float16* __restrict__ emb, const uint2* __restrict__ y14,
    const int2* __restrict__ sdp,
    const uint2* __restrict__ nf,
    const float* __restrict__ W1, const float* __restrict__ B1,
    const _Float16* __restrict__ w2f,
    float* __restrict__ aggs, float* __restrict__ aggx,
    float* __restrict__ aggy, float* __restrict__ aggz, int E)
{
    __shared__ _Float16 w2s[20480];   // 40 KB
    {
        half8* dstv = (half8*)w2s;
        const half8* srcv = (const half8*)w2f;
        #pragma unroll
        for (int k = 0; k < 10; k++)
            dstv[threadIdx.x + k*256] = srcv[threadIdx.x + k*256];
    }
    // NO barrier yet — prefetch + MLP1 below cover the staging latency.

    int wave  = (blockIdx.x * blockDim.x + threadIdx.x) >> 6;
    int lane  = threadIdx.x & 63;
    int wbase = wave * 16;
    bool active = wbase < E;
    int q   = lane >> 4;
    int col = lane & 15;

    int eb = wbase + q*4;
    int d[4], si[4];
    float y1x[4], y1y[4], y1z[4];
    #pragma unroll
    for (int r = 0; r < 4; r++) {
        int ee = eb + r;
        int ec = (active && ee < E) ? ee : 0;
        int2 sv = sdp[ec];
        si[r] = sv.x;
        d[r]  = (active && ee < E) ? sv.y : -1;
        uint2 yv = y14[ec];
        float dummy;
        unp2(yv.x, y1x[r], y1y[r]);
        unp2(yv.y, y1z[r], dummy);
    }

    // batched nf prefetch, hidden under MLP1 (R11)
    uint2 pf[4][4];
    #pragma unroll
    for (int r = 0; r < 4; r++) {
        size_t nb = (size_t)si[r] * 64 + col;
        pf[r][0] = nf[nb];
        pf[r][1] = nf[nb + 16];
        pf[r][2] = nf[nb + 32];
        pf[r][3] = nf[nb + 48];
    }

    half8 afrag[2];
    mlp1_afrag(emb, W1, B1, active ? (wbase + col) : 0, q, afrag);

    int dnq = __shfl_down(d[0], 16);
    int nd3 = (q == 3) ? -1 : dnq;
    int df = d[0], dl = d[3];
    bool U = (df == dl);
    int dlp = __shfl_up(dl, 16);
    bool link = (q > 0) && (dlp == df);

    __syncthreads();   // staging complete; all waves arrive

    #pragma unroll
    for (int cg = 0; cg < 4; cg++) {
        float4v acc[5];
        #pragma unroll
        for (int p = 0; p < 5; p++) acc[p] = (float4v){0.f, 0.f, 0.f, 0.f};
        const _Float16* wbp = w2s + ((size_t)cg*5*2*64*8) + (size_t)lane*8;
        #pragma unroll
        for (int p = 0; p < 5; p++) {
            half8 bf0 = *(const half8*)(wbp + ((size_t)(p*2 + 0))*64*8);
            half8 bf1 = *(const half8*)(wbp + ((size_t)(p*2 + 1))*64*8);
            acc[p] = __builtin_amdgcn_mfma_f32_16x16x32_f16(afrag[0], bf0, acc[p], 0, 0, 0);
            acc[p] = __builtin_amdgcn_mfma_f32_16x16x32_f16(afrag[1], bf1, acc[p], 0, 0, 0);
        }
        if (!active) continue;
        int c = cg*16 + col;

        float ms[4], mx[4], my[4], mz[4];
        #pragma unroll
        for (int r = 0; r < 4; r++) {
            float fsx, fvx, fvy, fvz;
            unp2(pf[r][cg].x, fsx, fvx);
            unp2(pf[r][cg].y, fvy, fvz);
            float yx = y1x[r], yy = y1y[r], yz = y1z[r];
            float w1 = acc[0][r], w2 = acc[1][r], w3 = acc[2][r];
            float w4 = acc[3][r], w5 = acc[4][r];
            float vdoty = fvx*yx + fvy*yy + fvz*yz;
            ms[r] = w1*fsx + w2*vdoty*(1.0f/SQRT3);
            float cx = fvy*yz - fvz*yy;
            float cy = fvz*yx - fvx*yz;
            float cz = fvx*yy - fvy*yx;
            mx[r] = w3*fsx*yx + w4*fvx + w5*cx*(1.0f/SQRT2);
            my[r] = w3*fsx*yy + w4*fvy + w5*cy*(1.0f/SQRT2);
            mz[r] = w3*fsx*yz + w4*fvz + w5*cz*(1.0f/SQRT2);
        }
        #pragma unroll
        for (int r = 1; r < 4; r++) {
            if (d[r] == d[r-1]) {
                ms[r] += ms[r-1]; mx[r] += mx[r-1];
                my[r] += my[r-1]; mz[r] += mz[r-1];
            }
        }
        float Cs = 0.f, Cx = 0.f, Cy = 0.f, Cz = 0.f;
        #pragma unroll
        for (int it = 0; it < 3; it++) {
            float es = ms[3] + (U ? Cs : 0.f);
            float ex = mx[3] + (U ? Cx : 0.f);
            float ey = my[3] + (U ? Cy : 0.f);
            float ez = mz[3] + (U ? Cz : 0.f);
            float ts = __shfl_up(es, 16);
            float tx = __shfl_up(ex, 16);
            float ty = __shfl_up(ey, 16);
            float tz = __shfl_up(ez, 16);
            Cs = link ? ts : 0.f; Cx = link ? tx : 0.f;
            Cy = link ? ty : 0.f; Cz = link ? tz : 0.f;
        }
        bool hr = true;
        #pragma unroll
        for (int r = 0; r < 4; r++) {
            if (r > 0) hr = hr && (d[r] == d[r-1]);
            float fs = ms[r] + (hr ? Cs : 0.f);
            float fx = mx[r] + (hr ? Cx : 0.f);
            float fy = my[r] + (hr ? Cy : 0.f);
            float fz = mz[r] + (hr ? Cz : 0.f);
            int ndx = (r < 3) ? d[r+1] : nd3;
            if (ndx != d[r] && d[r] >= 0) {
                size_t ai = (size_t)d[r]*64 + c;
                atomicAdd(aggs + ai, fs);
                atomicAdd(aggx + ai, fx);
                atomicAdd(aggy + ai, fy);
                atomicAdd(aggz + ai, fz);
            }
        }
    }
}

// ---------------------------------------------------------------------------
// MFMA node update: one wave per 16 nodes (R12). R17: wgtf staged in LDS
// (24.6KB). first=1 (L0): residual s from wlin[type], v = 0. Epilogue zeroes
// agg in place; fused energy projection on last layer.
// ---------------------------------------------------------------------------
__global__ __launch_bounds__(256) void node_update_mfma(
    uint2* __restrict__ nf,
    float* __restrict__ aggs, float* __restrict__ aggx,
    float* __restrict__ aggy, float* __restrict__ aggz,
    const _Float16* __restrict__ wgtf,
    const int* __restrict__ type, const float* __restrict__ wlin,
    const float* __restrict__ wl12,
    float* __restrict__ out, int first, int do_out, int N)
{
    __shared__ _Float16 wgs[12288];   // 24.6 KB
    {
        half8* dstv = (half8*)wgs;
        const half8* srcv = (const half8*)wgtf;
        #pragma unroll
        for (int k = 0; k < 6; k++)
            dstv[threadIdx.x + k*256] = srcv[threadIdx.x + k*256];
    }
    // barrier after A-frag loads below

    int wave  = (blockIdx.x * blockDim.x + threadIdx.x) >> 6;
    int lane  = threadIdx.x & 63;
    int wbase = wave * 16;
    bool active = wbase < N;
    int q = lane >> 4, col = lane & 15;

    int nodeA = active ? (wbase + col) : 0;
    if (nodeA >= N) nodeA = N - 1;
    size_t nb = (size_t)nodeA * 64 + q * 8;
    half8 af0[2], af1[2], af2[2], af3[2];
    #pragma unroll
    for (int kh = 0; kh < 2; kh++) {
        const float* p0 = aggs + nb + kh*32;
        const float* p1 = aggx + nb + kh*32;
        const float* p2 = aggy + nb + kh*32;
        const float* p3 = aggz + nb + kh*32;
        float4 a0 = *(const float4*)p0, b0 = *(const float4*)(p0+4);
        float4 a1 = *(const float4*)p1, b1 = *(const float4*)(p1+4);
        float4 a2 = *(const float4*)p2, b2 = *(const float4*)(p2+4);
        float4 a3 = *(const float4*)p3, b3 = *(const float4*)(p3+4);
        af0[kh][0]=(_Float16)(a0.x*INV_SQRT_DEG); af0[kh][1]=(_Float16)(a0.y*INV_SQRT_DEG);
        af0[kh][2]=(_Float16)(a0.z*INV_SQRT_DEG); af0[kh][3]=(_Float16)(a0.w*INV_SQRT_DEG);
        af0[kh][4]=(_Float16)(b0.x*INV_SQRT_DEG); af0[kh][5]=(_Float16)(b0.y*INV_SQRT_DEG);
        af0[kh][6]=(_Float16)(b0.z*INV_SQRT_DEG); af0[kh][7]=(_Float16)(b0.w*INV_SQRT_DEG);
        af1[kh][0]=(_Float16)(a1.x*INV_SQRT_DEG); af1[kh][1]=(_Float16)(a1.y*INV_SQRT_DEG);
        af1[kh][2]=(_Float16)(a1.z*INV_SQRT_DEG); af1[kh][3]=(_Float16)(a1.w*INV_SQRT_DEG);
        af1[kh][4]=(_Float16)(b1.x*INV_SQRT_DEG); af1[kh][5]=(_Float16)(b1.y*INV_SQRT_DEG);
        af1[kh][6]=(_Float16)(b1.z*INV_SQRT_DEG); af1[kh][7]=(_Float16)(b1.w*INV_SQRT_DEG);
        af2[kh][0]=(_Float16)(a2.x*INV_SQRT_DEG); af2[kh][1]=(_Float16)(a2.y*INV_SQRT_DEG);
        af2[kh][2]=(_Float16)(a2.z*INV_SQRT_DEG); af2[kh][3]=(_Float16)(a2.w*INV_SQRT_DEG);
        af2[kh][4]=(_Float16)(b2.x*INV_SQRT_DEG); af2[kh][5]=(_Float16)(b2.y*INV_SQRT_DEG);
        af2[kh][6]=(_Float16)(b2.z*INV_SQRT_DEG); af2[kh][7]=(_Float16)(b2.w*INV_SQRT_DEG);
        af3[kh][0]=(_Float16)(a3.x*INV_SQRT_DEG); af3[kh][1]=(_Float16)(a3.y*INV_SQRT_DEG);
        af3[kh][2]=(_Float16)(a3.z*INV_SQRT_DEG); af3[kh][3]=(_Float16)(a3.w*INV_SQRT_DEG);
        af3[kh][4]=(_Float16)(b3.x*INV_SQRT_DEG); af3[kh][5]=(_Float16)(b3.y*INV_SQRT_DEG);
        af3[kh][6]=(_Float16)(b3.z*INV_SQRT_DEG); af3[kh][7]=(_Float16)(b3.w*INV_SQRT_DEG);
    }

    int tt[4];
    #pragma unroll
    for (int r = 0; r < 4; r++) {
        int nd = wbase + q*4 + r;
        tt[r] = type[(active && nd < N) ? nd : 0];
    }

    __syncthreads();   // wgtf staged; all waves arrive

    float epart[4] = {0.f, 0.f, 0.f, 0.f};

    #pragma unroll
    for (int cg = 0; cg < 4; cg++) {
        const _Float16* bp = wgs + (size_t)lane * 8;
        half8 bg0 = *(const half8*)(bp + ((size_t)((0*4 + cg)*2 + 0))*512);
        half8 bg1 = *(const half8*)(bp + ((size_t)((0*4 + cg)*2 + 1))*512);
        half8 bs0 = *(const half8*)(bp + ((size_t)((1*4 + cg)*2 + 0))*512);
        half8 bs1 = *(const half8*)(bp + ((size_t)((1*4 + cg)*2 + 1))*512);
        half8 bv0 = *(const half8*)(bp + ((size_t)((2*4 + cg)*2 + 0))*512);
        half8 bv1 = *(const half8*)(bp + ((size_t)((2*4 + cg)*2 + 1))*512);
        float4v ag = {0,0,0,0}, as = {0,0,0,0};
        float4v ox = {0,0,0,0}, oy = {0,0,0,0}, oz = {0,0,0,0};
        ag = __builtin_amdgcn_mfma_f32_16x16x32_f16(af0[0], bg0, ag, 0, 0, 0);
        ag = __builtin_amdgcn_mfma_f32_16x16x32_f16(af0[1], bg1, ag, 0, 0, 0);
        as = __builtin_amdgcn_mfma_f32_16x16x32_f16(af0[0], bs0, as, 0, 0, 0);
        as = __builtin_amdgcn_mfma_f32_16x16x32_f16(af0[1], bs1, as, 0, 0, 0);
        ox = __builtin_amdgcn_mfma_f32_16x16x32_f16(af1[0], bv0, ox, 0, 0, 0);
        ox = __builtin_amdgcn_mfma_f32_16x16x32_f16(af1[1], bv1, ox, 0, 0, 0);
        oy = __builtin_amdgcn_mfma_f32_16x16x32_f16(af2[0], bv0, oy, 0, 0, 0);
        oy = __builtin_amdgcn_mfma_f32_16x16x32_f16(af2[1], bv1, oy, 0, 0, 0);
        oz = __builtin_amdgcn_mfma_f32_16x16x32_f16(af3[0], bv0, oz, 0, 0, 0);
        oz = __builtin_amdgcn_mfma_f32_16x16x32_f16(af3[1], bv1, oz, 0, 0, 0);

        if (!active) continue;
        int c = cg*16 + col;
        float wlc = wl12[c];
        #pragma unroll
        for (int r = 0; r < 4; r++) {
            int nd = wbase + q*4 + r;
            bool wr = nd < N;
            size_t ni = (size_t)nd*64 + c;
            float sx, vx, vy, vz;
            if (first) {
                sx = wlin[tt[r]*64 + c];
                vx = 0.f; vy = 0.f; vz = 0.f;
            } else {
                uint2 cur = nf[wr ? ni : 0];
                unp2(cur.x, sx, vx);
                unp2(cur.y, vy, vz);
            }
            float gate = sigmoidf_(ag[r]);
            sx += siluf_(as[r]);
            vx += ox[r] * gate;
            vy += oy[r] * gate;
            vz += oz[r] * gate;
            if (wr) {
                uint2 nv;
                nv.x = pk2(sx, vx);
                nv.y = pk2(vy, vz);
                nf[ni] = nv;
                aggs[ni] = 0.f;   // in-place zero replaces per-layer memset
                aggx[ni] = 0.f;
                aggy[ni] = 0.f;
                aggz[ni] = 0.f;
                epart[r] = fmaf(sx, wlc, epart[r]);
            }
        }
    }
    if (do_out && active) {
        #pragma unroll
        for (int r = 0; r < 4; r++) {
            float e = epart[r];
            e += __shfl_xor(e, 1);
            e += __shfl_xor(e, 2);
            e += __shfl_xor(e, 4);
            e += __shfl_xor(e, 8);
            int nd = wbase + q*4 + r;
            if (col == 0 && nd < N) out[nd] = e;
        }
    }
}

extern "C" void kernel_launch(void* const* d_in, const int* in_sizes, int n_in,
                              void* d_out, int out_size, void* d_ws, size_t ws_size,
                              hipStream_t stream)
{
    const int*   atom_type = (const int*)  d_in[0];
    const float* pos       = (const float*)d_in[1];
    const int*   src       = (const int*)  d_in[2];
    const int*   dst       = (const int*)  d_in[3];
    const float* cs        = (const float*)d_in[4];
    const float* cell      = (const float*)d_in[5];
    const int*   img       = (const int*)  d_in[6];
    const float* wlin_in   = (const float*)d_in[7];
    const float* mw1       = (const float*)d_in[8];
    const float* mb1       = (const float*)d_in[9];
    const float* mw2       = (const float*)d_in[10];
    const float* wss       = (const float*)d_in[11];
    const float* wsv       = (const float*)d_in[12];
    const float* wg        = (const float*)d_in[13];
    const float* wl1       = (const float*)d_in[14];
    const float* wl2       = (const float*)d_in[15];
    int N = in_sizes[0];
    int E = in_sizes[2];

    char* w = (char*)d_ws;
    _Float16* emb = (_Float16*)w; w += (size_t)E * 8 * sizeof(_Float16);  // 8.2 MB
    uint2*  y14  = (uint2*)w;  w += (size_t)E * sizeof(uint2);            // 4.1 MB
    int2*   sdp  = (int2*)w;   w += (size_t)E * sizeof(int2);             // 4.1 MB
    uint2*  nf   = (uint2*)w;  w += (size_t)N * 64 * sizeof(uint2);       // 8.2 MB
    float*  agg  = (float*)w;  w += (size_t)N * 64 * 4 * sizeof(float);   // 16.4 MB
    _Float16* w2f  = (_Float16*)w; w += (size_t)3 * 20480 * sizeof(_Float16);
    _Float16* wgtf = (_Float16*)w; w += (size_t)3 * 3 * 4096 * sizeof(_Float16);
    float*  wl12 = (float*)w;  w += 64 * sizeof(float);
    int*    deg  = (int*)w;    w += (size_t)N * sizeof(int);
    int*    curs = (int*)w;    w += (size_t)N * sizeof(int);

    size_t NC = (size_t)N * 64;
    float* aggs = agg;
    float* aggx = agg + NC;
    float* aggy = agg + 2*NC;
    float* aggz = agg + 3*NC;

    hipMemsetAsync(deg, 0, (size_t)N * sizeof(int), stream);
    hipMemsetAsync(agg, 0, NC * 4 * sizeof(float), stream);  // L0 only;
                                                             // node_update
                                                             // zeroes in place
    count_deg<<<(E/4 + 255) / 256, 256, 0, stream>>>(dst, deg, E);
    scan_deg<<<1, 1024, 0, stream>>>(deg, curs, N);
    int prep_n = 3*20480 + 3*3*4096;
    prep_weights<<<(prep_n + 255) / 256, 256, 0, stream>>>(
        mw2, w2f, wg, wss, wsv, wgtf, wl1, wl2, wl12);
    edge_pre_scatter<<<(E + 255) / 256, 256, 0, stream>>>(
        pos, src, dst, cs, cell, img, curs, emb, y14, sdp, E);

    int eblocks = (E + 63) / 64;   // 4 waves/block, 16 edges/wave
    int nblocks = (N + 63) / 64;   // 4 waves/block, 16 nodes/wave

    // ---- Layer 0: v==0 specialization ----
    edge_msg_mfma_l0<<<eblocks, 256, 0, stream>>>(
        emb, y14, sdp, atom_type, wlin_in,
        mw1, mb1, w2f, aggs, aggx, aggy, aggz, E);
    node_update_mfma<<<nblocks, 256, 0, stream>>>(
        nf, aggs, aggx, aggy, aggz, wgtf, atom_type, wlin_in, wl12,
        (float*)d_out, 1, 0, N);

    // ---- Layers 1..2 ----
    for (int L = 1; L < 3; L++) {
        edge_msg_mfma<<<eblocks, 256, 0, stream>>>(
            emb, y14, sdp, nf,
            mw1 + L * 8 * 64, mb1 + L * 64, w2f + (size_t)L * 20480,
            aggs, aggx, aggy, aggz, E);
        node_update_mfma<<<nblocks, 256, 0, stream>>>(
            nf, aggs, aggx, aggy, aggz,
            wgtf + (size_t)L * 12288, atom_type, wlin_in, wl12,
            (float*)d_out, 0, (L == 2) ? 1 : 0, N);
    }
}

// Round 18
// 480.578 us; speedup vs baseline: 1.0449x; 1.0449x over previous
//
#include <hip/hip_runtime.h>
#include <hip/hip_fp16.h>
#include <math.h>

#define NUM_BASIS 8
#define SQRT3 1.7320508075688772f
#define SQRT2 1.4142135623730951f
#define INV_SQRT_DEG 0.17677669529663687f   // 1/sqrt(32)
#define PI_F 3.14159265358979323846f

typedef _Float16 half8 __attribute__((ext_vector_type(8)));
typedef float float4v __attribute__((ext_vector_type(4)));

__device__ __forceinline__ float sigmoidf_(float x) { return 1.0f / (1.0f + __expf(-x)); }
__device__ __forceinline__ float siluf_(float x) { return x * sigmoidf_(x); }

__device__ __forceinline__ void unp2(unsigned u, float& a, float& b) {
    __half2 h = *reinterpret_cast<__half2*>(&u);
    float2 f = __half22float2(h);
    a = f.x; b = f.y;
}
__device__ __forceinline__ unsigned pk2(float a, float b) {
    __half2 h = __floats2half2_rn(a, b);
    return *reinterpret_cast<unsigned*>(&h);
}

// ---------------------------------------------------------------------------
// CSR build: degree count (4 edges/thread) -> single-block scan -> scatter
// ---------------------------------------------------------------------------
__global__ __launch_bounds__(256) void count_deg(
    const int* __restrict__ dst, int* __restrict__ deg, int E)
{
    int base = (blockIdx.x * blockDim.x + threadIdx.x) * 4;
    if (base + 3 < E) {
        int4 d4 = *(const int4*)(dst + base);
        atomicAdd(&deg[d4.x], 1);
        atomicAdd(&deg[d4.y], 1);
        atomicAdd(&deg[d4.z], 1);
        atomicAdd(&deg[d4.w], 1);
    } else {
        for (int e = base; e < E; e++) atomicAdd(&deg[dst[e]], 1);
    }
}

__global__ __launch_bounds__(1024) void scan_deg(
    const int* __restrict__ deg, int* __restrict__ cursor, int N)
{
    __shared__ int wsum[16];
    __shared__ int carry_s, tot_s;
    int tid = threadIdx.x;
    int wid = tid >> 6, lane = tid & 63;
    if (tid == 0) carry_s = 0;
    __syncthreads();
    for (int base = 0; base < N; base += 16384) {
        int i0 = base + tid * 16;
        int v[16];
        int sum = 0;
        #pragma unroll
        for (int k = 0; k < 16; k++) {
            int i = i0 + k;
            v[k] = (i < N) ? deg[i] : 0;
            sum += v[k];
        }
        int incl = sum;
        #pragma unroll
        for (int off = 1; off < 64; off <<= 1) {
            int t = __shfl_up(incl, off);
            if (lane >= off) incl += t;
        }
        if (lane == 63) wsum[wid] = incl;
        __syncthreads();
        if (wid == 0 && lane < 16) {
            int wv = wsum[lane];
            int wincl = wv;
            #pragma unroll
            for (int off = 1; off < 16; off <<= 1) {
                int t = __shfl_up(wincl, off);
                if (lane >= off) wincl += t;
            }
            wsum[lane] = wincl - wv;
            if (lane == 15) tot_s = wincl;
        }
        __syncthreads();
        int carry = carry_s;
        int run = carry + wsum[wid] + incl - sum;   // exclusive prefix at i0
        #pragma unroll
        for (int k = 0; k < 16; k++) {
            int i = i0 + k;
            if (i < N) cursor[i] = run;
            run += v[k];
        }
        __syncthreads();
        if (tid == 0) carry_s = carry + tot_s;
        __syncthreads();
    }
}

// Per-edge geometry + radial embedding, scattered directly into CSR slots.
// emb stored f16x8 (16B), y14 stored f16x4 (8B).
__global__ __launch_bounds__(256) void edge_pre_scatter(
    const float* __restrict__ pos, const int* __restrict__ src,
    const int* __restrict__ dst, const float* __restrict__ cs,
    const float* __restrict__ cell, const int* __restrict__ img,
    int* __restrict__ cursor, _Float16* __restrict__ emb,
    uint2* __restrict__ y14, int2* __restrict__ sdp, int E)
{
    int e = blockIdx.x * blockDim.x + threadIdx.x;
    if (e >= E) return;
    int si = src[e], di = dst[e];
    int slot = atomicAdd(&cursor[di], 1);
    sdp[slot] = make_int2(si, di);
    float vx = pos[di*3+0] - pos[si*3+0];
    float vy = pos[di*3+1] - pos[si*3+1];
    float vz = pos[di*3+2] - pos[si*3+2];
    float c0 = cs[(size_t)e*3+0], c1 = cs[(size_t)e*3+1], c2 = cs[(size_t)e*3+2];
    const float* M = cell + (size_t)img[si] * 9;
    vx += c0*M[0] + c1*M[3] + c2*M[6];
    vy += c0*M[1] + c1*M[4] + c2*M[7];
    vz += c0*M[2] + c1*M[5] + c2*M[8];
    float r  = sqrtf(vx*vx + vy*vy + vz*vz);
    float rs = fmaxf(r, 1e-9f);
    float inv = 1.0f / rs;
    uint2 yv;
    yv.x = pk2(SQRT3*vx*inv, SQRT3*vy*inv);
    yv.y = pk2(SQRT3*vz*inv, 0.f);
    y14[slot] = yv;
    // polynomial cutoff p=6: 1 - 28 x^6 + 48 x^7 - 21 x^8 (0 for x>=1)
    float x = r * (1.0f / 5.0f);
    float x2 = x*x, x6 = x2*x2*x2;
    float fc = 1.0f - 28.0f*x6 + 48.0f*x6*x - 21.0f*x6*x2;
    if (x >= 1.0f) fc = 0.0f;
    float pre = sqrtf(2.0f / 5.0f) * inv * fc;
    float t = PI_F * rs * (1.0f / 5.0f);
    half8 ev;
    #pragma unroll
    for (int n = 1; n <= NUM_BASIS; n++)
        ev[n-1] = (_Float16)(pre * __sinf((float)n * t));
    *(half8*)(emb + (size_t)slot*NUM_BASIS) = ev;
}

// ---------------------------------------------------------------------------
// Weight prep: w2f (W2 -> f16 B-frag), wgtf (Wg/Ws/Wv -> f16 B-frag),
// wl12 = Wl1 @ Wl2.
// ---------------------------------------------------------------------------
__global__ __launch_bounds__(256) void prep_weights(
    const float* __restrict__ W2, _Float16* __restrict__ w2f,
    const float* __restrict__ Wg, const float* __restrict__ Ws,
    const float* __restrict__ Wv, _Float16* __restrict__ wgtf,
    const float* __restrict__ Wl1, const float* __restrict__ Wl2,
    float* __restrict__ wl12)
{
    int idx = blockIdx.x * blockDim.x + threadIdx.x;
    if (idx < 64) {
        float a = 0.f;
        #pragma unroll
        for (int j = 0; j < 16; j++) a = fmaf(Wl1[idx*16 + j], Wl2[j], a);
        wl12[idx] = a;
    }
    if (idx < 3 * 20480) {
        int L  = idx / 20480;
        int r  = idx % 20480;
        int cg = r / 5120;
        int r2 = r % 5120;
        int p  = r2 / 1024;
        int r3 = r2 % 1024;
        int kh = r3 / 512;
        int r4 = r3 % 512;
        int lane = r4 / 8;
        int j  = r4 % 8;
        int k = kh*32 + (lane >> 4)*8 + j;
        int n = p*64 + cg*16 + (lane & 15);
        w2f[idx] = (_Float16)W2[(size_t)L*20480 + k*320 + n];
    } else if (idx < 3*20480 + 3*3*4096) {
        int idx2 = idx - 3*20480;
        int L   = idx2 / 12288;
        int rem = idx2 % 12288;
        int mat = rem / 4096;
        int r2  = rem % 4096;
        int cg  = r2 / 1024;
        int r3  = r2 % 1024;
        int kh  = r3 / 512;
        int r4  = r3 % 512;
        int lane = r4 / 8;
        int j   = r4 % 8;
        int k = kh*32 + (lane >> 4)*8 + j;
        int n = cg*16 + (lane & 15);
        const float* src = (mat == 0) ? Wg : (mat == 1) ? Ws : Wv;
        wgtf[idx2] = (_Float16)src[(size_t)L*4096 + k*64 + n];
    }
}

// ---------------------------------------------------------------------------
// A-frag MLP1: h[k] for edge eA (f16 emb input), k = kh*32 + q*8 + j
// ---------------------------------------------------------------------------
__device__ __forceinline__ void mlp1_afrag(
    const _Float16* __restrict__ emb, const float* __restrict__ W1,
    const float* __restrict__ B1, int eA, int q, half8 afrag[2])
{
    half8 ev = *(const half8*)(emb + (size_t)eA*8);
    float em[8];
    #pragma unroll
    for (int j = 0; j < 8; j++) em[j] = (float)ev[j];
    #pragma unroll
    for (int kh = 0; kh < 2; kh++) {
        int kb = kh*32 + q*8;
        float hv[8];
        float4 b0 = *(const float4*)(B1 + kb);
        float4 b1 = *(const float4*)(B1 + kb + 4);
        hv[0]=b0.x; hv[1]=b0.y; hv[2]=b0.z; hv[3]=b0.w;
        hv[4]=b1.x; hv[5]=b1.y; hv[6]=b1.z; hv[7]=b1.w;
        #pragma unroll
        for (int jj = 0; jj < 8; jj++) {
            float4 wa = *(const float4*)(W1 + jj*64 + kb);
            float4 wb = *(const float4*)(W1 + jj*64 + kb + 4);
            hv[0] = fmaf(em[jj], wa.x, hv[0]);
            hv[1] = fmaf(em[jj], wa.y, hv[1]);
            hv[2] = fmaf(em[jj], wa.z, hv[2]);
            hv[3] = fmaf(em[jj], wa.w, hv[3]);
            hv[4] = fmaf(em[jj], wb.x, hv[4]);
            hv[5] = fmaf(em[jj], wb.y, hv[5]);
            hv[6] = fmaf(em[jj], wb.z, hv[6]);
            hv[7] = fmaf(em[jj], wb.w, hv[7]);
        }
        #pragma unroll
        for (int j = 0; j < 8; j++)
            afrag[kh][j] = (_Float16)siluf_(hv[j]);
    }
}

// R18: EARLY staging barrier restored (R16 structure). R17's late barrier
// regressed: s_barrier pins s_waitcnt vmcnt(0), which drained the R11 nf
// prefetch loads too — defeating the ILP hiding. With the barrier immediately
// after staging, only the 10 staging loads drain; prefetch stays in flight
// under MLP1. Cross-quad carry kept (R14). agg PLANAR (R9). No VGPR caps (R4).
// ---------------------------------------------------------------------------
// Layer-0 edge kernel: v == 0 exactly -> only w1/w3 paths, 16 MFMA, no nf.
// ---------------------------------------------------------------------------
__global__ __launch_bounds__(256) void edge_msg_mfma_l0(
    const _Float16* __restrict__ emb, const uint2* __restrict__ y14,
    const int2* __restrict__ sdp,
    const int* __restrict__ type, const float* __restrict__ wlin,
    const float* __restrict__ W1, const float* __restrict__ B1,
    const _Float16* __restrict__ w2f,
    float* __restrict__ aggs, float* __restrict__ aggx,
    float* __restrict__ aggy, float* __restrict__ aggz, int E)
{
    __shared__ _Float16 w2s[20480];   // 40 KB
    {
        half8* dstv = (half8*)w2s;
        const half8* srcv = (const half8*)w2f;
        #pragma unroll
        for (int k = 0; k < 10; k++)
            dstv[threadIdx.x + k*256] = srcv[threadIdx.x + k*256];
    }
    __syncthreads();

    int wave  = (blockIdx.x * blockDim.x + threadIdx.x) >> 6;
    int lane  = threadIdx.x & 63;
    int wbase = wave * 16;
    if (wbase >= E) return;
    int q   = lane >> 4;
    int col = lane & 15;

    int eb = wbase + q*4;
    int d[4], tt[4];
    float y1x[4], y1y[4], y1z[4];
    #pragma unroll
    for (int r = 0; r < 4; r++) {
        int2 sv = sdp[eb + r];
        tt[r] = type[sv.x];
        d[r]  = sv.y;
        uint2 yv = y14[eb + r];
        float dummy;
        unp2(yv.x, y1x[r], y1y[r]);
        unp2(yv.y, y1z[r], dummy);
    }

    half8 afrag[2];
    mlp1_afrag(emb, W1, B1, wbase + col, q, afrag);

    int dnq = __shfl_down(d[0], 16);      // next quad's first dst
    int nd3 = (q == 3) ? -1 : dnq;        // q3 reg3: forced tail
    int df = d[0], dl = d[3];
    bool U = (df == dl);
    int dlp = __shfl_up(dl, 16);
    bool link = (q > 0) && (dlp == df);

    #pragma unroll
    for (int cg = 0; cg < 4; cg++) {
        float4v a1 = {0,0,0,0}, a3 = {0,0,0,0};
        const _Float16* wbp = w2s + ((size_t)cg*5*2*64*8) + (size_t)lane*8;
        {
            half8 b10 = *(const half8*)(wbp + ((size_t)(0*2 + 0))*64*8);
            half8 b11 = *(const half8*)(wbp + ((size_t)(0*2 + 1))*64*8);
            half8 b30 = *(const half8*)(wbp + ((size_t)(2*2 + 0))*64*8);
            half8 b31 = *(const half8*)(wbp + ((size_t)(2*2 + 1))*64*8);
            a1 = __builtin_amdgcn_mfma_f32_16x16x32_f16(afrag[0], b10, a1, 0, 0, 0);
            a1 = __builtin_amdgcn_mfma_f32_16x16x32_f16(afrag[1], b11, a1, 0, 0, 0);
            a3 = __builtin_amdgcn_mfma_f32_16x16x32_f16(afrag[0], b30, a3, 0, 0, 0);
            a3 = __builtin_amdgcn_mfma_f32_16x16x32_f16(afrag[1], b31, a3, 0, 0, 0);
        }
        int c = cg*16 + col;

        float ms[4], mx[4], my[4], mz[4];
        #pragma unroll
        for (int r = 0; r < 4; r++) {
            float s = wlin[tt[r]*64 + c];
            float w3s = a3[r] * s;
            ms[r] = a1[r] * s;
            mx[r] = w3s * y1x[r];
            my[r] = w3s * y1y[r];
            mz[r] = w3s * y1z[r];
        }
        #pragma unroll
        for (int r = 1; r < 4; r++) {
            if (d[r] == d[r-1]) {
                ms[r] += ms[r-1]; mx[r] += mx[r-1];
                my[r] += my[r-1]; mz[r] += mz[r-1];
            }
        }
        // cross-quad carry (chains up to 4 quads -> 3 iterations)
        float Cs = 0.f, Cx = 0.f, Cy = 0.f, Cz = 0.f;
        #pragma unroll
        for (int it = 0; it < 3; it++) {
            float es = ms[3] + (U ? Cs : 0.f);
            float ex = mx[3] + (U ? Cx : 0.f);
            float ey = my[3] + (U ? Cy : 0.f);
            float ez = mz[3] + (U ? Cz : 0.f);
            float ts = __shfl_up(es, 16);
            float tx = __shfl_up(ex, 16);
            float ty = __shfl_up(ey, 16);
            float tz = __shfl_up(ez, 16);
            Cs = link ? ts : 0.f; Cx = link ? tx : 0.f;
            Cy = link ? ty : 0.f; Cz = link ? tz : 0.f;
        }
        bool hr = true;
        #pragma unroll
        for (int r = 0; r < 4; r++) {
            if (r > 0) hr = hr && (d[r] == d[r-1]);
            float fs = ms[r] + (hr ? Cs : 0.f);
            float fx = mx[r] + (hr ? Cx : 0.f);
            float fy = my[r] + (hr ? Cy : 0.f);
            float fz = mz[r] + (hr ? Cz : 0.f);
            int ndx = (r < 3) ? d[r+1] : nd3;
            if (ndx != d[r] && d[r] >= 0) {
                size_t ai = (size_t)d[r]*64 + c;
                atomicAdd(aggs + ai, fs);
                atomicAdd(aggx + ai, fx);
                atomicAdd(aggy + ai, fy);
                atomicAdd(aggz + ai, fz);
            }
        }
    }
}

// ---------------------------------------------------------------------------
// General MFMA edge kernel (layers >= 1): one wave per 16 CSR edges.
// R11 batched nf prefetch (ILP over MLP1). R16 early barrier.
// ---------------------------------------------------------------------------
__global__ __launch_bounds__(256) void edge_msg_mfma(
    const _Float16* __restrict__ emb, const uint2* __restrict__ y14,
    const int2* __restrict__ sdp,
    const uint2* __restrict__ nf,
    const float* __restrict__ W1, const float* __restrict__ B1,
    const _Float16* __restrict__ w2f,
    float* __restrict__ aggs, float* __restrict__ aggx,
    float* __restrict__ aggy, float* __restrict__ aggz, int E)
{
    __shared__ _Float16 w2s[20480];   // 40 KB
    {
        half8* dstv = (half8*)w2s;
        const half8* srcv = (const half8*)w2f;
        #pragma unroll
        for (int k = 0; k < 10; k++)
            dstv[threadIdx.x + k*256] = srcv[threadIdx.x + k*256];
    }
    __syncthreads();

    int wave  = (blockIdx.x * blockDim.x + threadIdx.x) >> 6;
    int lane  = threadIdx.x & 63;
    int wbase = wave * 16;
    if (wbase >= E) return;
    int q   = lane >> 4;
    int col = lane & 15;

    int eb = wbase + q*4;
    int d[4], si[4];
    float y1x[4], y1y[4], y1z[4];
    #pragma unroll
    for (int r = 0; r < 4; r++) {
        int2 sv = sdp[eb + r];
        si[r] = sv.x;
        d[r]  = sv.y;
        uint2 yv = y14[eb + r];
        float dummy;
        unp2(yv.x, y1x[r], y1y[r]);
        unp2(yv.y, y1z[r], dummy);
    }

    // batched nf prefetch, hidden under MLP1 (R11)
    uint2 pf[4][4];
    #pragma unroll
    for (int r = 0; r < 4; r++) {
        size_t nb = (size_t)si[r] * 64 + col;
        pf[r][0] = nf[nb];
        pf[r][1] = nf[nb + 16];
        pf[r][2] = nf[nb + 32];
        pf[r][3] = nf[nb + 48];
    }

    half8 afrag[2];
    mlp1_afrag(emb, W1, B1, wbase + col, q, afrag);

    int dnq = __shfl_down(d[0], 16);
    int nd3 = (q == 3) ? -1 : dnq;
    int df = d[0], dl = d[3];
    bool U = (df == dl);
    int dlp = __shfl_up(dl, 16);
    bool link = (q > 0) && (dlp == df);

    #pragma unroll
    for (int cg = 0; cg < 4; cg++) {
        float4v acc[5];
        #pragma unroll
        for (int p = 0; p < 5; p++) acc[p] = (float4v){0.f, 0.f, 0.f, 0.f};
        const _Float16* wbp = w2s + ((size_t)cg*5*2*64*8) + (size_t)lane*8;
        #pragma unroll
        for (int p = 0; p < 5; p++) {
            half8 bf0 = *(const half8*)(wbp + ((size_t)(p*2 + 0))*64*8);
            half8 bf1 = *(const half8*)(wbp + ((size_t)(p*2 + 1))*64*8);
            acc[p] = __builtin_amdgcn_mfma_f32_16x16x32_f16(afrag[0], bf0, acc[p], 0, 0, 0);
            acc[p] = __builtin_amdgcn_mfma_f32_16x16x32_f16(afrag[1], bf1, acc[p], 0, 0, 0);
        }
        int c = cg*16 + col;

        float ms[4], mx[4], my[4], mz[4];
        #pragma unroll
        for (int r = 0; r < 4; r++) {
            float fsx, fvx, fvy, fvz;
            unp2(pf[r][cg].x, fsx, fvx);
            unp2(pf[r][cg].y, fvy, fvz);
            float yx = y1x[r], yy = y1y[r], yz = y1z[r];
            float w1 = acc[0][r], w2 = acc[1][r], w3 = acc[2][r];
            float w4 = acc[3][r], w5 = acc[4][r];
            float vdoty = fvx*yx + fvy*yy + fvz*yz;
            ms[r] = w1*fsx + w2*vdoty*(1.0f/SQRT3);
            float cx = fvy*yz - fvz*yy;
            float cy = fvz*yx - fvx*yz;
            float cz = fvx*yy - fvy*yx;
            mx[r] = w3*fsx*yx + w4*fvx + w5*cx*(1.0f/SQRT2);
            my[r] = w3*fsx*yy + w4*fvy + w5*cy*(1.0f/SQRT2);
            mz[r] = w3*fsx*yz + w4*fvz + w5*cz*(1.0f/SQRT2);
        }
        #pragma unroll
        for (int r = 1; r < 4; r++) {
            if (d[r] == d[r-1]) {
                ms[r] += ms[r-1]; mx[r] += mx[r-1];
                my[r] += my[r-1]; mz[r] += mz[r-1];
            }
        }
        float Cs = 0.f, Cx = 0.f, Cy = 0.f, Cz = 0.f;
        #pragma unroll
        for (int it = 0; it < 3; it++) {
            float es = ms[3] + (U ? Cs : 0.f);
            float ex = mx[3] + (U ? Cx : 0.f);
            float ey = my[3] + (U ? Cy : 0.f);
            float ez = mz[3] + (U ? Cz : 0.f);
            float ts = __shfl_up(es, 16);
            float tx = __shfl_up(ex, 16);
            float ty = __shfl_up(ey, 16);
            float tz = __shfl_up(ez, 16);
            Cs = link ? ts : 0.f; Cx = link ? tx : 0.f;
            Cy = link ? ty : 0.f; Cz = link ? tz : 0.f;
        }
        bool hr = true;
        #pragma unroll
        for (int r = 0; r < 4; r++) {
            if (r > 0) hr = hr && (d[r] == d[r-1]);
            float fs = ms[r] + (hr ? Cs : 0.f);
            float fx = mx[r] + (hr ? Cx : 0.f);
            float fy = my[r] + (hr ? Cy : 0.f);
            float fz = mz[r] + (hr ? Cz : 0.f);
            int ndx = (r < 3) ? d[r+1] : nd3;
            if (ndx != d[r] && d[r] >= 0) {
                size_t ai = (size_t)d[r]*64 + c;
                atomicAdd(aggs + ai, fs);
                atomicAdd(aggx + ai, fx);
                atomicAdd(aggy + ai, fy);
                atomicAdd(aggz + ai, fz);
            }
        }
    }
}

// ---------------------------------------------------------------------------
// MFMA node update: one wave per 16 nodes (R12). wgtf staged in LDS (R17,
// kept: A-frag loads consumed before the barrier, so no prefetch is drained).
// first=1 (L0): residual s from wlin[type], v = 0. Epilogue zeroes agg in
// place; fused energy projection on last layer.
// ---------------------------------------------------------------------------
__global__ __launch_bounds__(256) void node_update_mfma(
    uint2* __restrict__ nf,
    float* __restrict__ aggs, float* __restrict__ aggx,
    float* __restrict__ aggy, float* __restrict__ aggz,
    const _Float16* __restrict__ wgtf,
    const int* __restrict__ type, const float* __restrict__ wlin,
    const float* __restrict__ wl12,
    float* __restrict__ out, int first, int do_out, int N)
{
    __shared__ _Float16 wgs[12288];   // 24.6 KB
    {
        half8* dstv = (half8*)wgs;
        const half8* srcv = (const half8*)wgtf;
        #pragma unroll
        for (int k = 0; k < 6; k++)
            dstv[threadIdx.x + k*256] = srcv[threadIdx.x + k*256];
    }

    int wave  = (blockIdx.x * blockDim.x + threadIdx.x) >> 6;
    int lane  = threadIdx.x & 63;
    int wbase = wave * 16;
    bool active = wbase < N;
    int q = lane >> 4, col = lane & 15;

    int nodeA = active ? (wbase + col) : 0;
    if (nodeA >= N) nodeA = N - 1;
    size_t nb = (size_t)nodeA * 64 + q * 8;
    half8 af0[2], af1[2], af2[2], af3[2];
    #pragma unroll
    for (int kh = 0; kh < 2; kh++) {
        const float* p0 = aggs + nb + kh*32;
        const float* p1 = aggx + nb + kh*32;
        const float* p2 = aggy + nb + kh*32;
        const float* p3 = aggz + nb + kh*32;
        float4 a0 = *(const float4*)p0, b0 = *(const float4*)(p0+4);
        float4 a1 = *(const float4*)p1, b1 = *(const float4*)(p1+4);
        float4 a2 = *(const float4*)p2, b2 = *(const float4*)(p2+4);
        float4 a3 = *(const float4*)p3, b3 = *(const float4*)(p3+4);
        af0[kh][0]=(_Float16)(a0.x*INV_SQRT_DEG); af0[kh][1]=(_Float16)(a0.y*INV_SQRT_DEG);
        af0[kh][2]=(_Float16)(a0.z*INV_SQRT_DEG); af0[kh][3]=(_Float16)(a0.w*INV_SQRT_DEG);
        af0[kh][4]=(_Float16)(b0.x*INV_SQRT_DEG); af0[kh][5]=(_Float16)(b0.y*INV_SQRT_DEG);
        af0[kh][6]=(_Float16)(b0.z*INV_SQRT_DEG); af0[kh][7]=(_Float16)(b0.w*INV_SQRT_DEG);
        af1[kh][0]=(_Float16)(a1.x*INV_SQRT_DEG); af1[kh][1]=(_Float16)(a1.y*INV_SQRT_DEG);
        af1[kh][2]=(_Float16)(a1.z*INV_SQRT_DEG); af1[kh][3]=(_Float16)(a1.w*INV_SQRT_DEG);
        af1[kh][4]=(_Float16)(b1.x*INV_SQRT_DEG); af1[kh][5]=(_Float16)(b1.y*INV_SQRT_DEG);
        af1[kh][6]=(_Float16)(b1.z*INV_SQRT_DEG); af1[kh][7]=(_Float16)(b1.w*INV_SQRT_DEG);
        af2[kh][0]=(_Float16)(a2.x*INV_SQRT_DEG); af2[kh][1]=(_Float16)(a2.y*INV_SQRT_DEG);
        af2[kh][2]=(_Float16)(a2.z*INV_SQRT_DEG); af2[kh][3]=(_Float16)(a2.w*INV_SQRT_DEG);
        af2[kh][4]=(_Float16)(b2.x*INV_SQRT_DEG); af2[kh][5]=(_Float16)(b2.y*INV_SQRT_DEG);
        af2[kh][6]=(_Float16)(b2.z*INV_SQRT_DEG); af2[kh][7]=(_Float16)(b2.w*INV_SQRT_DEG);
        af3[kh][0]=(_Float16)(a3.x*INV_SQRT_DEG); af3[kh][1]=(_Float16)(a3.y*INV_SQRT_DEG);
        af3[kh][2]=(_Float16)(a3.z*INV_SQRT_DEG); af3[kh][3]=(_Float16)(a3.w*INV_SQRT_DEG);
        af3[kh][4]=(_Float16)(b3.x*INV_SQRT_DEG); af3[kh][5]=(_Float16)(b3.y*INV_SQRT_DEG);
        af3[kh][6]=(_Float16)(b3.z*INV_SQRT_DEG); af3[kh][7]=(_Float16)(b3.w*INV_SQRT_DEG);
    }

    int tt[4];
    #pragma unroll
    for (int r = 0; r < 4; r++) {
        int nd = wbase + q*4 + r;
        tt[r] = type[(active && nd < N) ? nd : 0];
    }

    __syncthreads();   // wgs staged; all waves arrive

    float epart[4] = {0.f, 0.f, 0.f, 0.f};

    #pragma unroll
    for (int cg = 0; cg < 4; cg++) {
        const _Float16* bp = wgs + (size_t)lane * 8;
        half8 bg0 = *(const half8*)(bp + ((size_t)((0*4 + cg)*2 + 0))*512);
        half8 bg1 = *(const half8*)(bp + ((size_t)((0*4 + cg)*2 + 1))*512);
        half8 bs0 = *(const half8*)(bp + ((size_t)((1*4 + cg)*2 + 0))*512);
        half8 bs1 = *(const half8*)(bp + ((size_t)((1*4 + cg)*2 + 1))*512);
        half8 bv0 = *(const half8*)(bp + ((size_t)((2*4 + cg)*2 + 0))*512);
        half8 bv1 = *(const half8*)(bp + ((size_t)((2*4 + cg)*2 + 1))*512);
        float4v ag = {0,0,0,0}, as = {0,0,0,0};
        float4v ox = {0,0,0,0}, oy = {0,0,0,0}, oz = {0,0,0,0};
        ag = __builtin_amdgcn_mfma_f32_16x16x32_f16(af0[0], bg0, ag, 0, 0, 0);
        ag = __builtin_amdgcn_mfma_f32_16x16x32_f16(af0[1], bg1, ag, 0, 0, 0);
        as = __builtin_amdgcn_mfma_f32_16x16x32_f16(af0[0], bs0, as, 0, 0, 0);
        as = __builtin_amdgcn_mfma_f32_16x16x32_f16(af0[1], bs1, as, 0, 0, 0);
        ox = __builtin_amdgcn_mfma_f32_16x16x32_f16(af1[0], bv0, ox, 0, 0, 0);
        ox = __builtin_amdgcn_mfma_f32_16x16x32_f16(af1[1], bv1, ox, 0, 0, 0);
        oy = __builtin_amdgcn_mfma_f32_16x16x32_f16(af2[0], bv0, oy, 0, 0, 0);
        oy = __builtin_amdgcn_mfma_f32_16x16x32_f16(af2[1], bv1, oy, 0, 0, 0);
        oz = __builtin_amdgcn_mfma_f32_16x16x32_f16(af3[0], bv0, oz, 0, 0, 0);
        oz = __builtin_amdgcn_mfma_f32_16x16x32_f16(af3[1], bv1, oz, 0, 0, 0);

        if (!active) continue;
        int c = cg*16 + col;
        float wlc = wl12[c];
        #pragma unroll
        for (int r = 0; r < 4; r++) {
            int nd = wbase + q*4 + r;
            bool wr = nd < N;
            size_t ni = (size_t)nd*64 + c;
            float sx, vx, vy, vz;
            if (first) {
                sx = wlin[tt[r]*64 + c];
                vx = 0.f; vy = 0.f; vz = 0.f;
            } else {
                uint2 cur = nf[wr ? ni : 0];
                unp2(cur.x, sx, vx);
                unp2(cur.y, vy, vz);
            }
            float gate = sigmoidf_(ag[r]);
            sx += siluf_(as[r]);
            vx += ox[r] * gate;
            vy += oy[r] * gate;
            vz += oz[r] * gate;
            if (wr) {
                uint2 nv;
                nv.x = pk2(sx, vx);
                nv.y = pk2(vy, vz);
                nf[ni] = nv;
                aggs[ni] = 0.f;   // in-place zero replaces per-layer memset
                aggx[ni] = 0.f;
                aggy[ni] = 0.f;
                aggz[ni] = 0.f;
                epart[r] = fmaf(sx, wlc, epart[r]);
            }
        }
    }
    if (do_out && active) {
        #pragma unroll
        for (int r = 0; r < 4; r++) {
            float e = epart[r];
            e += __shfl_xor(e, 1);
            e += __shfl_xor(e, 2);
            e += __shfl_xor(e, 4);
            e += __shfl_xor(e, 8);
            int nd = wbase + q*4 + r;
            if (col == 0 && nd < N) out[nd] = e;
        }
    }
}

extern "C" void kernel_launch(void* const* d_in, const int* in_sizes, int n_in,
                              void* d_out, int out_size, void* d_ws, size_t ws_size,
                              hipStream_t stream)
{
    const int*   atom_type = (const int*)  d_in[0];
    const float* pos       = (const float*)d_in[1];
    const int*   src       = (const int*)  d_in[2];
    const int*   dst       = (const int*)  d_in[3];
    const float* cs        = (const float*)d_in[4];
    const float* cell      = (const float*)d_in[5];
    const int*   img       = (const int*)  d_in[6];
    const float* wlin_in   = (const float*)d_in[7];
    const float* mw1       = (const float*)d_in[8];
    const float* mb1       = (const float*)d_in[9];
    const float* mw2       = (const float*)d_in[10];
    const float* wss       = (const float*)d_in[11];
    const float* wsv       = (const float*)d_in[12];
    const float* wg        = (const float*)d_in[13];
    const float* wl1       = (const float*)d_in[14];
    const float* wl2       = (const float*)d_in[15];
    int N = in_sizes[0];
    int E = in_sizes[2];

    char* w = (char*)d_ws;
    _Float16* emb = (_Float16*)w; w += (size_t)E * 8 * sizeof(_Float16);  // 8.2 MB
    uint2*  y14  = (uint2*)w;  w += (size_t)E * sizeof(uint2);            // 4.1 MB
    int2*   sdp  = (int2*)w;   w += (size_t)E * sizeof(int2);             // 4.1 MB
    uint2*  nf   = (uint2*)w;  w += (size_t)N * 64 * sizeof(uint2);       // 8.2 MB
    float*  agg  = (float*)w;  w += (size_t)N * 64 * 4 * sizeof(float);   // 16.4 MB
    _Float16* w2f  = (_Float16*)w; w += (size_t)3 * 20480 * sizeof(_Float16);
    _Float16* wgtf = (_Float16*)w; w += (size_t)3 * 3 * 4096 * sizeof(_Float16);
    float*  wl12 = (float*)w;  w += 64 * sizeof(float);
    int*    deg  = (int*)w;    w += (size_t)N * sizeof(int);
    int*    curs = (int*)w;    w += (size_t)N * sizeof(int);

    size_t NC = (size_t)N * 64;
    float* aggs = agg;
    float* aggx = agg + NC;
    float* aggy = agg + 2*NC;
    float* aggz = agg + 3*NC;

    hipMemsetAsync(deg, 0, (size_t)N * sizeof(int), stream);
    hipMemsetAsync(agg, 0, NC * 4 * sizeof(float), stream);  // L0 only;
                                                             // node_update
                                                             // zeroes in place
    count_deg<<<(E/4 + 255) / 256, 256, 0, stream>>>(dst, deg, E);
    scan_deg<<<1, 1024, 0, stream>>>(deg, curs, N);
    int prep_n = 3*20480 + 3*3*4096;
    prep_weights<<<(prep_n + 255) / 256, 256, 0, stream>>>(
        mw2, w2f, wg, wss, wsv, wgtf, wl1, wl2, wl12);
    edge_pre_scatter<<<(E + 255) / 256, 256, 0, stream>>>(
        pos, src, dst, cs, cell, img, curs, emb, y14, sdp, E);

    int eblocks = (E + 63) / 64;   // 4 waves/block, 16 edges/wave
    int nblocks = (N + 63) / 64;   // 4 waves/block, 16 nodes/wave

    // ---- Layer 0: v==0 specialization ----
    edge_msg_mfma_l0<<<eblocks, 256, 0, stream>>>(
        emb, y14, sdp, atom_type, wlin_in,
        mw1, mb1, w2f, aggs, aggx, aggy, aggz, E);
    node_update_mfma<<<nblocks, 256, 0, stream>>>(
        nf, aggs, aggx, aggy, aggz, wgtf, atom_type, wlin_in, wl12,
        (float*)d_out, 1, 0, N);

    // ---- Layers 1..2 ----
    for (int L = 1; L < 3; L++) {
        edge_msg_mfma<<<eblocks, 256, 0, stream>>>(
            emb, y14, sdp, nf,
            mw1 + L * 8 * 64, mb1 + L * 64, w2f + (size_t)L * 20480,
            aggs, aggx, aggy, aggz, E);
        node_update_mfma<<<nblocks, 256, 0, stream>>>(
            nf, aggs, aggx, aggy, aggz,
            wgtf + (size_t)L * 12288, atom_type, wlin_in, wl12,
            (float*)d_out, 0, (L == 2) ? 1 : 0, N);
    }
}